// Round 6
// baseline (622.130 us; speedup 1.0000x reference)
//
#include <hip/hip_runtime.h>
#include <hip/hip_bf16.h>
#include <stdint.h>

// ---------------------------------------------------------------------------
// RegressionNet: cost-volume + 3x conv-BN-relu + 2x FC, bf16 MFMA pipeline.
// R5: conv rewritten as stage-X-once + LDS tap-shift. A chunk (256x64) staged
//     once per K-chunk; 9 taps read row-shifted fragments (halo via addr
//     redirect to LDS zero pad). Staging/step drops 64->36KB == MFMA-balanced.
//     One barrier per 64 MFMA; B fragments register-resident per step.
// ---------------------------------------------------------------------------

typedef unsigned short ushort_t;
typedef __attribute__((ext_vector_type(8))) short     bf16x8;
typedef __attribute__((ext_vector_type(8))) unsigned short u16x8;
typedef __attribute__((ext_vector_type(4))) unsigned short u16x4;
typedef __attribute__((ext_vector_type(4))) float     f32x4;

#define NB   64
#define NC   256
#define NP   256
#define KCV  256
#define KP1  1152
#define NOUT 512
#define NROWS 16384
#define KFC  131072
#define NF   1024
#define KSPL 32      // fc1 k-splits

__device__ __forceinline__ unsigned short f2bf(float x) {
  union { float f; unsigned u; } c; c.f = x;
  unsigned r = c.u + 0x7FFFu + ((c.u >> 16) & 1u);
  return (unsigned short)(r >> 16);
}
__device__ __forceinline__ float b2f(unsigned short u) {
  union { unsigned u; float f; } c; c.u = ((unsigned)u) << 16; return c.f;
}

__device__ __forceinline__ void gl_lds16(const void* g, void* l) {
  __builtin_amdgcn_global_load_lds(
      (const __attribute__((address_space(1))) unsigned int*)g,
      (__attribute__((address_space(3))) unsigned int*)l, 16, 0, 0);
}

__device__ __forceinline__ f32x4 mfma16(bf16x8 a, bf16x8 b, f32x4 c) {
  return __builtin_amdgcn_mfma_f32_16x16x32_bf16(a, b, c, 0, 0, 0);
}

// ---------------------------------------------------------------------------
// l2-normalize over channels; write pos-major bf16 [b][pos][c].
// ---------------------------------------------------------------------------
__global__ __launch_bounds__(256) void l2norm_t(
    const float* __restrict__ f1, const float* __restrict__ f2,
    ushort_t* __restrict__ AT, ushort_t* __restrict__ N2T)
{
  const float* src = blockIdx.y ? f2 : f1;
  ushort_t*    dst = blockIdx.y ? N2T : AT;
  const int b = blockIdx.x, t = threadIdx.x;
  const float* sb = src + (size_t)b * NC * NP;
  float sq = 0.f;
  for (int c = 0; c < NC; ++c) { float v = sb[c * NP + t]; sq += v * v; }
  float sc = 1.f / fmaxf(sqrtf(sq), 1e-12f);
  ushort_t* db = dst + ((size_t)b * NP + t) * NC;
  for (int c0 = 0; c0 < NC; c0 += 8) {
    u16x8 pk;
#pragma unroll
    for (int q = 0; q < 8; ++q) pk[q] = f2bf(sb[(c0 + q) * NP + t] * sc);
    *(u16x8*)(db + c0) = pk;
  }
}

// ---------------------------------------------------------------------------
// Pack conv weights (OUT, Cin, 3, 3) fp32 -> [tap][out][cin(pad Kp)] bf16.
// ---------------------------------------------------------------------------
__global__ __launch_bounds__(256) void pack_w(
    const float* __restrict__ W, ushort_t* __restrict__ Wp,
    int Cin, int Kp, int total)
{
  int p = blockIdx.x * 256 + threadIdx.x;
  if (p >= total) return;
  int tap = p / (NOUT * Kp);
  int rem = p - tap * (NOUT * Kp);
  int o   = rem / Kp;
  int cin = rem - o * Kp;
  float v = (cin < Cin) ? W[((size_t)o * Cin + cin) * 9 + tap] : 0.f;
  Wp[p] = f2bf(v);
}

// ---------------------------------------------------------------------------
// Cost volume: per-b GEMM (pos x uv over channels), band-gather epilogue.
// ---------------------------------------------------------------------------
__global__ __launch_bounds__(256) void cv_gemm(
    const ushort_t* __restrict__ AT,
    const ushort_t* __restrict__ N2T,
    ushort_t* __restrict__ costT,
    const ushort_t* __restrict__ zerot)
{
  __shared__ ushort_t As[128 * 64];
  __shared__ ushort_t Bs[128 * 64];
  const int tid = threadIdx.x, lane = tid & 63, wave = tid >> 6;
  const int wr = wave >> 1, wc = wave & 1;
  const int la = lane & 15, lb = lane >> 4;
  const int b  = blockIdx.z;
  const int m0 = blockIdx.y * 128;
  const int n0 = blockIdx.x * 128;

  {
    const int iMin = blockIdx.y * 8, iMax = iMin + 7;
    const int uMin = n0 / 48, uMax = (n0 + 127) / 48;
    if (uMax < iMin || uMin > iMax + 32) return;
  }

  f32x4 acc[4][4];
#pragma unroll
  for (int i = 0; i < 4; ++i)
#pragma unroll
    for (int j = 0; j < 4; ++j) acc[i][j] = (f32x4){0.f, 0.f, 0.f, 0.f};

  const ushort_t* srcA[4];
  const ushort_t* srcB[4];
#pragma unroll
  for (int s = 0; s < 4; ++s) {
    int idx = tid + (s << 8);
    int row = idx >> 3, c16 = idx & 7;
    srcA[s] = AT + ((size_t)b * NP + m0 + row) * NC + c16 * 8;
    int uv = n0 + row;
    int u = uv / 48, v = uv - u * 48;
    int oi = u - 16, oj = v - 16;
    bool val = ((unsigned)oi < 16u) & ((unsigned)oj < 16u);
    srcB[s] = val ? (N2T + ((size_t)b * NP + oi * 16 + oj) * NC + c16 * 8)
                  : (const ushort_t*)0;
  }

  for (int kc = 0; kc < KCV; kc += 64) {
#pragma unroll
    for (int s = 0; s < 4; ++s) {
      int idx = tid + (s << 8);
      gl_lds16(srcA[s] + kc, &As[idx * 8]);
      const ushort_t* g = srcB[s] ? srcB[s] + kc : zerot;
      gl_lds16(g, &Bs[idx * 8]);
    }
    __syncthreads();
#pragma unroll
    for (int kk = 0; kk < 2; ++kk) {
      bf16x8 af[4], bfv[4];
#pragma unroll
      for (int mi = 0; mi < 4; ++mi)
        af[mi] = *(const bf16x8*)&As[(wr * 64 + mi * 16 + la) * 64 + kk * 32 + lb * 8];
#pragma unroll
      for (int ni = 0; ni < 4; ++ni)
        bfv[ni] = *(const bf16x8*)&Bs[(wc * 64 + ni * 16 + la) * 64 + kk * 32 + lb * 8];
#pragma unroll
      for (int mi = 0; mi < 4; ++mi)
#pragma unroll
        for (int ni = 0; ni < 4; ++ni)
          acc[mi][ni] = mfma16(af[mi], bfv[ni], acc[mi][ni]);
    }
    __syncthreads();
  }

  const float sc = 1.f / 256.f;
#pragma unroll
  for (int ni = 0; ni < 4; ++ni) {
    int uv = n0 + wc * 64 + ni * 16 + la;
    int u = uv / 48, v = uv - u * 48;
#pragma unroll
    for (int mi = 0; mi < 4; ++mi) {
      int ij = m0 + wr * 64 + mi * 16 + lb * 4;
#pragma unroll
      for (int r = 0; r < 4; ++r) {
        int ijr = ij + r;
        int i = ijr >> 4, j = ijr & 15;
        int dy = u - i, dx = v - j;
        if ((unsigned)dy < 33u && (unsigned)dx < 33u) {
          float vv = acc[mi][ni][r] * sc;
          vv = vv > 0.f ? vv : 0.01f * vv;
          costT[((size_t)b * NP + ijr) * KP1 + dy * 33 + dx] = f2bf(vv);
        }
      }
    }
  }
}

// ---------------------------------------------------------------------------
// Conv 3x3 via stage-X-once + LDS tap shift. 2-way K-split, BM=256(=image),
// BN=256, chunk=64ch. Block 512 = 8 waves (2M x 4N); per-wave 128x64 out.
// LDS: A dbuf 2x32KB + W dbuf 2x32KB + 128B zero pad.
// Per step (tap,chunk): 4 reg phases, 64 MFMA, ONE barrier. W staged 1 step
// ahead (4 gl_lds), A' 2 steps ahead at tap==7. Halo rows/cols -> addr
// redirect to zero pad (i-check uniform per (wr,mi); j-check lanes 0/15 only).
// ---------------------------------------------------------------------------
__global__ __launch_bounds__(512, 1) void conv_tap(
    const ushort_t* __restrict__ X, const ushort_t* __restrict__ Wp,
    const float* __restrict__ bias, ushort_t* __restrict__ Y0,
    ushort_t* __restrict__ Y1, const int K, const int Kh, const int nc)
{
  __shared__ ushort_t lds[65600];   // A: [0,32768), W: [32768,65536), zeros: [65536,65600)
  const int tid = threadIdx.x;
  const int lane = tid & 63, wave = tid >> 6;
  const int wr = wave >> 2, wc = wave & 3;
  const int la = lane & 15, lb = lane >> 4;

  // XCD swizzle (256 blocks): logical L -> (g, b, n0)
  const int bid = blockIdx.x;
  const int L = ((bid & 7) << 5) + (bid >> 3);
  const int g = L >> 7;
  const int rem = L & 127;
  const int b = rem >> 1;
  const int n0 = (rem & 1) << 8;
  const int koff0 = g * Kh;

  // zero pad
  if (tid < 8) *(u16x8*)&lds[65536 + tid * 8] = (u16x8){0,0,0,0,0,0,0,0};

  // staging bases (pre-swizzled global source, linear LDS dest)
  const ushort_t* abase[4];
  const ushort_t* bbase[4];
#pragma unroll
  for (int s = 0; s < 4; ++s) {
    int idx = tid + (s << 9);
    int row = idx >> 3, ck = idx & 7;
    abase[s] = X + (size_t)(b * NP + row) * K + ((ck ^ (row & 7)) << 3);
    int loc = (idx >> 3) & 63, ks = idx & 7;
    int rB = ((s & 1) << 7) + ((loc >> 5) << 6) + ((s >> 1) << 5) + (loc & 31);
    bbase[s] = Wp + (size_t)(n0 + rB) * K + ((ks ^ (rB & 7)) << 3);
  }

  // B read offsets (B rows are all == la mod 8)
  const int ckB0 = ((0 + lb) ^ (la & 7)) << 3;
  const int ckB1 = ((4 + lb) ^ (la & 7)) << 3;
  const int wread = (wc >> 1) * 4096 + (wc & 1) * 2048 + la * 64;

  f32x4 acc[8][4];
#pragma unroll
  for (int i = 0; i < 8; ++i)
#pragma unroll
    for (int j = 0; j < 4; ++j) acc[i][j] = (f32x4){0.f, 0.f, 0.f, 0.f};

  const int nsteps = nc * 9;

  // prologue: stage A[0] and W[step 0]
#pragma unroll
  for (int s = 0; s < 4; ++s)
    gl_lds16(abase[s] + koff0, &lds[(tid + (s << 9)) * 8]);
  {
    size_t wko = (size_t)koff0;   // tap 0, chunk 0
#pragma unroll
    for (int s = 0; s < 4; ++s)
      gl_lds16(bbase[s] + wko, &lds[32768 + (tid + (s << 9)) * 8]);
  }
  asm volatile("s_waitcnt vmcnt(0)" ::: "memory");
  __builtin_amdgcn_s_barrier();

  for (int c = 0; c < nc; ++c) {
    const int aC = (c & 1) << 14;           // A buf element base
    ushort_t* an = &lds[((c + 1) & 1) << 14];
    for (int tap = 0; tap < 9; ++tap) {
      const int step = c * 9 + tap;
      const int wC = 32768 + ((step & 1) << 14);
      ushort_t* wn = &lds[32768 + (((step + 1) & 1) << 14)];
      const bool has_next = step < nsteps - 1;
      const bool stageA = (tap == 7) && (c < nc - 1);
      // next step's W source offset
      int tapN = (tap < 8) ? tap + 1 : 0;
      int cN   = (tap < 8) ? c : c + 1;
      size_t wkoN = (size_t)tapN * NOUT * K + koff0 + cN * 64;
      int akoN = koff0 + (c + 1) * 64;

      // tap geometry
      const int ty = tap / 3, tx = tap - 3 * ty;
      const int dA = (ty - 1) * 16 + (tx - 1);
      const int sx = (la + dA) & 7;
      const int ckA0 = ((lb ^ sx) << 3);
      const int ckA1 = (((4 + lb) ^ sx) << 3);
      const int rbase = wr * 128 + la + dA;
      const int ibase = wr * 8 + ty - 1;
      const bool jok = !((tx == 0) & (la == 0)) & !((tx == 2) & (la == 15));

      bf16x8 Af[4][2];
      bf16x8 b01_00, b01_01, b01_10, b01_11;
      bf16x8 b23_00, b23_01, b23_10, b23_11;

      // ---- P0: Af(mi0-3) + B01 reads; stage W slots 0,1 ----
#pragma unroll
      for (int mi = 0; mi < 4; ++mi) {
        bool ok = jok && ((unsigned)(ibase + mi) < 16u);
        int r = (rbase + mi * 16) * 64;
        int a0 = ok ? aC + r + ckA0 : 65536;
        int a1 = ok ? aC + r + ckA1 : 65536;
        Af[mi][0] = *(const bf16x8*)&lds[a0];
        Af[mi][1] = *(const bf16x8*)&lds[a1];
      }
      b01_00 = *(const bf16x8*)&lds[wC + wread + 0    + ckB0];
      b01_01 = *(const bf16x8*)&lds[wC + wread + 0    + ckB1];
      b01_10 = *(const bf16x8*)&lds[wC + wread + 1024 + ckB0];
      b01_11 = *(const bf16x8*)&lds[wC + wread + 1024 + ckB1];
      if (has_next) {
        gl_lds16(bbase[0] + wkoN, &wn[(tid + 0 * 512) * 8]);
        gl_lds16(bbase[1] + wkoN, &wn[(tid + 1 * 512) * 8]);
      }
      asm volatile("s_waitcnt lgkmcnt(0)" ::: "memory");
      __builtin_amdgcn_sched_barrier(0);
      __builtin_amdgcn_s_setprio(1);
#pragma unroll
      for (int mi = 0; mi < 4; ++mi) {
        acc[mi][0] = mfma16(Af[mi][0], b01_00, acc[mi][0]);
        acc[mi][1] = mfma16(Af[mi][0], b01_10, acc[mi][1]);
      }
#pragma unroll
      for (int mi = 0; mi < 4; ++mi) {
        acc[mi][0] = mfma16(Af[mi][1], b01_01, acc[mi][0]);
        acc[mi][1] = mfma16(Af[mi][1], b01_11, acc[mi][1]);
      }
      __builtin_amdgcn_s_setprio(0);

      // ---- P1: B23 reads; stage W slots 2,3 (+A' 0,1 at tap==7) ----
      b23_00 = *(const bf16x8*)&lds[wC + 8192 + wread + 0    + ckB0];
      b23_01 = *(const bf16x8*)&lds[wC + 8192 + wread + 0    + ckB1];
      b23_10 = *(const bf16x8*)&lds[wC + 8192 + wread + 1024 + ckB0];
      b23_11 = *(const bf16x8*)&lds[wC + 8192 + wread + 1024 + ckB1];
      if (has_next) {
        gl_lds16(bbase[2] + wkoN, &wn[(tid + 2 * 512) * 8]);
        gl_lds16(bbase[3] + wkoN, &wn[(tid + 3 * 512) * 8]);
      }
      if (stageA) {
        gl_lds16(abase[0] + akoN, &an[(tid + 0 * 512) * 8]);
        gl_lds16(abase[1] + akoN, &an[(tid + 1 * 512) * 8]);
      }
      asm volatile("s_waitcnt lgkmcnt(0)" ::: "memory");
      __builtin_amdgcn_sched_barrier(0);
      __builtin_amdgcn_s_setprio(1);
#pragma unroll
      for (int mi = 0; mi < 4; ++mi) {
        acc[mi][2] = mfma16(Af[mi][0], b23_00, acc[mi][2]);
        acc[mi][3] = mfma16(Af[mi][0], b23_10, acc[mi][3]);
      }
#pragma unroll
      for (int mi = 0; mi < 4; ++mi) {
        acc[mi][2] = mfma16(Af[mi][1], b23_01, acc[mi][2]);
        acc[mi][3] = mfma16(Af[mi][1], b23_11, acc[mi][3]);
      }
      __builtin_amdgcn_s_setprio(0);

      // ---- P2: Af(mi4-7) reads (overwrite Af); stage A' 2,3 at tap==7 ----
#pragma unroll
      for (int mi = 0; mi < 4; ++mi) {
        bool ok = jok && ((unsigned)(ibase + 4 + mi) < 16u);
        int r = (rbase + (4 + mi) * 16) * 64;
        int a0 = ok ? aC + r + ckA0 : 65536;
        int a1 = ok ? aC + r + ckA1 : 65536;
        Af[mi][0] = *(const bf16x8*)&lds[a0];
        Af[mi][1] = *(const bf16x8*)&lds[a1];
      }
      if (stageA) {
        gl_lds16(abase[2] + akoN, &an[(tid + 2 * 512) * 8]);
        gl_lds16(abase[3] + akoN, &an[(tid + 3 * 512) * 8]);
      }
      asm volatile("s_waitcnt lgkmcnt(0)" ::: "memory");
      __builtin_amdgcn_sched_barrier(0);
      __builtin_amdgcn_s_setprio(1);
#pragma unroll
      for (int mi = 0; mi < 4; ++mi) {
        acc[4 + mi][0] = mfma16(Af[mi][0], b01_00, acc[4 + mi][0]);
        acc[4 + mi][1] = mfma16(Af[mi][0], b01_10, acc[4 + mi][1]);
      }
#pragma unroll
      for (int mi = 0; mi < 4; ++mi) {
        acc[4 + mi][0] = mfma16(Af[mi][1], b01_01, acc[4 + mi][0]);
        acc[4 + mi][1] = mfma16(Af[mi][1], b01_11, acc[4 + mi][1]);
      }
      __builtin_amdgcn_s_setprio(0);

      // ---- P3: MFMA only; counted vmcnt; step barrier ----
      __builtin_amdgcn_s_setprio(1);
#pragma unroll
      for (int mi = 0; mi < 4; ++mi) {
        acc[4 + mi][2] = mfma16(Af[mi][0], b23_00, acc[4 + mi][2]);
        acc[4 + mi][3] = mfma16(Af[mi][0], b23_10, acc[4 + mi][3]);
      }
#pragma unroll
      for (int mi = 0; mi < 4; ++mi) {
        acc[4 + mi][2] = mfma16(Af[mi][1], b23_01, acc[4 + mi][2]);
        acc[4 + mi][3] = mfma16(Af[mi][1], b23_11, acc[4 + mi][3]);
      }
      __builtin_amdgcn_s_setprio(0);
      if (has_next) {
        if (stageA) asm volatile("s_waitcnt vmcnt(4)" ::: "memory");
        else        asm volatile("s_waitcnt vmcnt(0)" ::: "memory");
      }
      __builtin_amdgcn_s_barrier();
    }
  }

  // epilogue: bias/2 + bf16 partial-Y store
  ushort_t* Yh = g ? Y1 : Y0;
#pragma unroll
  for (int ni = 0; ni < 4; ++ni) {
    int col = n0 + wc * 64 + ni * 16 + la;
    float bv = 0.5f * bias[col];
#pragma unroll
    for (int mi = 0; mi < 8; ++mi) {
      int row = b * NP + wr * 128 + mi * 16 + lb * 4;
#pragma unroll
      for (int r = 0; r < 4; ++r)
        Yh[(size_t)(row + r) * NOUT + col] = f2bf(acc[mi][ni][r] + bv);
    }
  }
}

// ---------------------------------------------------------------------------
// BN stats from the two bf16 partial halves. grid 512 x block 512.
// ---------------------------------------------------------------------------
__global__ __launch_bounds__(512) void bn_stat2(
    const ushort_t* __restrict__ Y0, const ushort_t* __restrict__ Y1,
    float* __restrict__ st)
{
  const int col = threadIdx.x;
  const size_t base = (size_t)blockIdx.x * 32 * NOUT;
  float s = 0.f, q = 0.f;
  for (int r = 0; r < 32; ++r) {
    float y = b2f(Y0[base + r * NOUT + col]) + b2f(Y1[base + r * NOUT + col]);
    s += y; q += y * y;
  }
  atomicAdd(&st[col], s);
  atomicAdd(&st[512 + col], q);
}

// ---------------------------------------------------------------------------
// BN apply (sum halves) + relu + bf16, layout [m][c]. grid 4096, block 256.
// ---------------------------------------------------------------------------
__global__ __launch_bounds__(256) void bn_apply2(
    const ushort_t* __restrict__ Y0, const ushort_t* __restrict__ Y1,
    const float* __restrict__ st, const float* __restrict__ g,
    const float* __restrict__ be, ushort_t* __restrict__ Xo)
{
  const size_t idx = (size_t)blockIdx.x * 256 + threadIdx.x;
  u16x8 a = *(const u16x8*)(Y0 + idx * 8);
  u16x8 c = *(const u16x8*)(Y1 + idx * 8);
  const int c0 = (int)((idx * 8) & 511);
  u16x8 pk;
#pragma unroll
  for (int q = 0; q < 8; ++q) {
    int cc = c0 + q;
    float y = b2f(a[q]) + b2f(c[q]);
    float mu  = st[cc] * (1.f / 16384.f);
    float var = st[512 + cc] * (1.f / 16384.f) - mu * mu;
    float s = rsqrtf(var + 1e-5f) * g[cc];
    pk[q] = f2bf(fmaxf((y - mu) * s + be[cc], 0.f));
  }
  *(u16x8*)(Xo + idx * 8) = pk;
}

// ---------------------------------------------------------------------------
// BN apply + relu + bf16, transposed to FC layout Xf[b][c*256+ij].
// ---------------------------------------------------------------------------
__global__ __launch_bounds__(256) void bn_apply2_t(
    const ushort_t* __restrict__ Y0, const ushort_t* __restrict__ Y1,
    const float* __restrict__ st, const float* __restrict__ g,
    const float* __restrict__ be, ushort_t* __restrict__ Xf)
{
  __shared__ ushort_t T[64][65];
  const int c0  = blockIdx.x * 64;
  const int ij0 = blockIdx.y * 64;
  const int b   = blockIdx.z;
  const int tid = threadIdx.x;

#pragma unroll
  for (int it = 0; it < 16; ++it) {
    int e = it * 256 + tid;
    int ij = e >> 6, c = e & 63;
    int cg = c0 + c;
    size_t off = ((size_t)(b * NP + ij0 + ij)) * NOUT + cg;
    float y = b2f(Y0[off]) + b2f(Y1[off]);
    float mu  = st[cg] * (1.f / 16384.f);
    float var = st[512 + cg] * (1.f / 16384.f) - mu * mu;
    float s = rsqrtf(var + 1e-5f) * g[cg];
    T[ij][c] = f2bf(fmaxf((y - mu) * s + be[cg], 0.f));
  }
  __syncthreads();
#pragma unroll
  for (int it = 0; it < 16; ++it) {
    int e = it * 256 + tid;
    int cr = e >> 6, ijc = e & 63;
    Xf[(size_t)b * KFC + (size_t)(c0 + cr) * NP + ij0 + ijc] = T[ijc][cr];
  }
}

// ---------------------------------------------------------------------------
// FC1: (64 x 131072) bf16 @ (1024 x 131072)^T, split-K slice stores.
// ---------------------------------------------------------------------------
__device__ __forceinline__ u16x8 pack8(float4 a, float4 b) {
  u16x8 r;
  r[0] = f2bf(a.x); r[1] = f2bf(a.y); r[2] = f2bf(a.z); r[3] = f2bf(a.w);
  r[4] = f2bf(b.x); r[5] = f2bf(b.y); r[6] = f2bf(b.z); r[7] = f2bf(b.w);
  return r;
}

__global__ __launch_bounds__(256) void fc1_gemm(
    const ushort_t* __restrict__ Xf, const float* __restrict__ Wf1,
    float* __restrict__ hacc)
{
  __shared__ ushort_t As[64 * 64];
  __shared__ ushort_t Bs[64 * 64];
  const int tid = threadIdx.x, lane = tid & 63, wave = tid >> 6;
  const int la = lane & 15, lb = lane >> 4;
  const int f0 = blockIdx.x * 64;
  const int k0 = blockIdx.y * 4096;

  f32x4 acc[4];
#pragma unroll
  for (int i = 0; i < 4; ++i) acc[i] = (f32x4){0.f, 0.f, 0.f, 0.f};

  const ushort_t* xrow[2];
#pragma unroll
  for (int s = 0; s < 2; ++s) {
    int idx = tid + (s << 8);
    xrow[s] = Xf + (size_t)(idx >> 3) * KFC + k0 + (idx & 7) * 8;
  }
  const int brow = tid >> 2, kseg = (tid & 3) * 16;
  const float* wrow = Wf1 + (size_t)(f0 + brow) * KFC + k0 + kseg;

  for (int kc = 0; kc < 4096; kc += 64) {
#pragma unroll
    for (int s = 0; s < 2; ++s) {
      int idx = tid + (s << 8);
      gl_lds16(xrow[s] + kc, &As[idx * 8]);
    }
    float4 w0 = *(const float4*)(wrow + kc);
    float4 w1 = *(const float4*)(wrow + kc + 4);
    float4 w2 = *(const float4*)(wrow + kc + 8);
    float4 w3 = *(const float4*)(wrow + kc + 12);
    *(u16x8*)&Bs[brow * 64 + kseg]     = pack8(w0, w1);
    *(u16x8*)&Bs[brow * 64 + kseg + 8] = pack8(w2, w3);
    __syncthreads();
#pragma unroll
    for (int kk = 0; kk < 2; ++kk) {
      bf16x8 bfv = *(const bf16x8*)&Bs[(wave * 16 + la) * 64 + kk * 32 + lb * 8];
#pragma unroll
      for (int mi = 0; mi < 4; ++mi) {
        bf16x8 av = *(const bf16x8*)&As[(mi * 16 + la) * 64 + kk * 32 + lb * 8];
        acc[mi] = mfma16(av, bfv, acc[mi]);
      }
    }
    __syncthreads();
  }

  float* slice = hacc + (size_t)blockIdx.y * NB * NF;
#pragma unroll
  for (int mi = 0; mi < 4; ++mi) {
    int row = mi * 16 + lb * 4;
#pragma unroll
    for (int r = 0; r < 4; ++r)
      slice[(size_t)(row + r) * NF + f0 + wave * 16 + la] = acc[mi][r];
  }
}

// ---------------------------------------------------------------------------
// FC2 + bias/relu; sums the 32 fc1 k-slices. grid 64, block 256.
// ---------------------------------------------------------------------------
__global__ __launch_bounds__(256) void fc2_out(
    const float* __restrict__ hacc, const float* __restrict__ bf1,
    const float* __restrict__ Wf2, const float* __restrict__ bf2,
    float* __restrict__ out)
{
  const int b = blockIdx.x, tid = threadIdx.x;
  float a[8];
#pragma unroll
  for (int o = 0; o < 8; ++o) a[o] = 0.f;
  for (int f = tid; f < NF; f += 256) {
    float hv = bf1[f];
#pragma unroll 4
    for (int s = 0; s < KSPL; ++s)
      hv += hacc[((size_t)s * NB + b) * NF + f];
    hv = fmaxf(hv, 0.f);
#pragma unroll
    for (int o = 0; o < 8; ++o) a[o] += hv * Wf2[o * NF + f];
  }
  __shared__ float red[8][256];
#pragma unroll
  for (int o = 0; o < 8; ++o) red[o][tid] = a[o];
  __syncthreads();
  for (int s = 128; s > 0; s >>= 1) {
    if (tid < s) {
#pragma unroll
      for (int o = 0; o < 8; ++o) red[o][tid] += red[o][tid + s];
    }
    __syncthreads();
  }
  if (tid < 8) out[b * 8 + tid] = red[tid][0] + bf2[tid];
}

// ---------------------------------------------------------------------------
extern "C" void kernel_launch(void* const* d_in, const int* in_sizes, int n_in,
                              void* d_out, int out_size, void* d_ws, size_t ws_size,
                              hipStream_t stream) {
  const float* f1  = (const float*)d_in[0];
  const float* f2  = (const float*)d_in[1];
  const float* W1  = (const float*)d_in[2];
  const float* b1  = (const float*)d_in[3];
  const float* g1  = (const float*)d_in[4];
  const float* be1 = (const float*)d_in[5];
  const float* W2  = (const float*)d_in[6];
  const float* b2  = (const float*)d_in[7];
  const float* g2  = (const float*)d_in[8];
  const float* be2 = (const float*)d_in[9];
  const float* W3  = (const float*)d_in[10];
  const float* b3  = (const float*)d_in[11];
  const float* g3  = (const float*)d_in[12];
  const float* be3 = (const float*)d_in[13];
  const float* Wf1 = (const float*)d_in[14];
  const float* bf1 = (const float*)d_in[15];
  const float* Wf2 = (const float*)d_in[16];
  const float* bf2 = (const float*)d_in[17];
  float* out = (float*)d_out;

  char* ws = (char*)d_ws;
  size_t off = 0;
  auto alloc = [&](size_t bytes) -> void* {
    void* p = ws + off;
    off += (bytes + 255) & ~(size_t)255;
    return p;
  };

  // zeroed region: zero tile + BN stats
  ushort_t* zerot = (ushort_t*)alloc(256);
  float* st1  = (float*)alloc(1024 * 4);
  float* st2  = (float*)alloc(1024 * 4);
  float* st3  = (float*)alloc(1024 * 4);
  const size_t zero_bytes = off;

  float* hacc = (float*)alloc((size_t)KSPL * NB * NF * 4);  // fully written
  const size_t SZ_AT   = (size_t)NB * NP * NC * 2;
  const size_t SZ_COST = (size_t)NB * NP * KP1 * 2;
  const size_t SZ_WP1  = (size_t)9 * NOUT * KP1 * 2;
  const size_t SZ_WP23 = (size_t)9 * NOUT * 512 * 2;
  ushort_t* AT    = (ushort_t*)alloc(SZ_AT);
  ushort_t* N2T   = (ushort_t*)alloc(SZ_AT);
  ushort_t* costT = (ushort_t*)alloc(SZ_COST);
  ushort_t* Wp1   = (ushort_t*)alloc(SZ_WP1);
  ushort_t* Wp2   = (ushort_t*)alloc(SZ_WP23);
  ushort_t* Wp3   = (ushort_t*)alloc(SZ_WP23);
  ushort_t* Yh0   = (ushort_t*)alloc((size_t)NROWS * NOUT * 2);
  ushort_t* Yh1   = (ushort_t*)alloc((size_t)NROWS * NOUT * 2);
  ushort_t* Xbuf  = (ushort_t*)alloc((size_t)NROWS * NOUT * 2);
  ushort_t* Xf    = (ushort_t*)alloc((size_t)NB * KFC * 2);

  hipMemsetAsync(ws, 0, zero_bytes, stream);
  hipMemsetAsync(costT, 0, SZ_COST, stream);

  l2norm_t<<<dim3(64, 2), 256, 0, stream>>>(f1, f2, AT, N2T);

  pack_w<<<(9 * NOUT * KP1 + 255) / 256, 256, 0, stream>>>(W1, Wp1, 1089, KP1, 9 * NOUT * KP1);
  pack_w<<<(9 * NOUT * 512 + 255) / 256, 256, 0, stream>>>(W2, Wp2, 512, 512, 9 * NOUT * 512);
  pack_w<<<(9 * NOUT * 512 + 255) / 256, 256, 0, stream>>>(W3, Wp3, 512, 512, 9 * NOUT * 512);

  cv_gemm<<<dim3(18, 2, 64), 256, 0, stream>>>(AT, N2T, costT, zerot);

  conv_tap<<<256, 512, 0, stream>>>(costT, Wp1, b1, Yh0, Yh1, KP1, 576, 9);
  bn_stat2<<<512, 512, 0, stream>>>(Yh0, Yh1, st1);
  bn_apply2<<<4096, 256, 0, stream>>>(Yh0, Yh1, st1, g1, be1, Xbuf);

  conv_tap<<<256, 512, 0, stream>>>(Xbuf, Wp2, b2, Yh0, Yh1, 512, 256, 4);
  bn_stat2<<<512, 512, 0, stream>>>(Yh0, Yh1, st2);
  bn_apply2<<<4096, 256, 0, stream>>>(Yh0, Yh1, st2, g2, be2, Xbuf);

  conv_tap<<<256, 512, 0, stream>>>(Xbuf, Wp3, b3, Yh0, Yh1, 512, 256, 4);
  bn_stat2<<<512, 512, 0, stream>>>(Yh0, Yh1, st3);
  bn_apply2_t<<<dim3(8, 4, 64), 256, 0, stream>>>(Yh0, Yh1, st3, g3, be3, Xf);

  fc1_gemm<<<dim3(16, KSPL), 256, 0, stream>>>(Xf, Wf1, hacc);
  fc2_out<<<64, 256, 0, stream>>>(hacc, bf1, Wf2, bf2, out);

  (void)in_sizes; (void)n_in; (void)out_size; (void)ws_size;
}